// Round 10
// baseline (223.717 us; speedup 1.0000x reference)
//
#include <hip/hip_runtime.h>
#include <math.h>

// Problem constants
#define B 8192
#define E 1024
#define D 384
#define H 64
#define R 8
#define NCHUNK 16
#define CHUNK_E 64
#define NPOS 17408          // 16384 + 8*128 per-router pad-to-128
#define NROW 25600          // 8192 evn rows + NPOS xun rows

// ws byte offsets (total ~20.1 MB)
#define WS_GCNT   0u          // int[256*8]  gate per-block top2 counts
#define WS_GPS    8192u       // float[256*8] gate per-block prob sums
#define WS_CNT    16384u      // int[8] counts
#define WS_OFFS   16416u      // int[8] padded segment bases
#define WS_TOP2   16448u      // int2[B]
#define WS_GW     81984u      // float2[B]
#define WS_POSM   147520u     // int2[B]
#define WS_LIST   213056u     // int[NPOS]
#define WS_EVN    282688u     // float[8*64*1024] evnT[r][h][e]
#define WS_XUN    2379840u    // float[NPOS*64]   xunP[pos][h]
#define WS_C      6836288u    // float[NPOS*16]   C[pos][chunk]
#define WS_BUFA   7950400u    // float[NROW*64]   K-half partial 0
#define WS_BUFB   14504000u   // float[NROW*64]   K-half partial 1

// ---------------- gate: lane = (sample, router); NO global atomics ---------
__global__ __launch_bounds__(256) void k_gate(
    const float* __restrict__ x, const float* __restrict__ gate_w,
    const float* __restrict__ gate_b, int2* __restrict__ top2,
    float2* __restrict__ gwv, int* __restrict__ gcnt, float* __restrict__ gps)
{
  __shared__ __align__(16) float gwT[R * 388];
  __shared__ float psl[R];
  __shared__ int   cl[R];
  int tid = threadIdx.x;
  for (int idx = tid; idx < D * R; idx += 256) {
    int k = idx >> 3, r = idx & 7;
    gwT[r * 388 + k] = gate_w[idx];
  }
  if (tid < R) { psl[tid] = 0.f; cl[tid] = 0; }
  __syncthreads();

  int l = tid & 63;
  int r = tid & 7;
  int b = blockIdx.x * 32 + (tid >> 3);
  float acc = gate_b[r];
  const float4* x4 = (const float4*)(x + (size_t)b * D);
  const float*  gr = gwT + r * 388;
#pragma unroll 4
  for (int q = 0; q < 96; ++q) {
    float4 xv = x4[q];
    float4 gv = *(const float4*)&gr[q * 4];
    acc = fmaf(xv.x, gv.x, acc);
    acc = fmaf(xv.y, gv.y, acc);
    acc = fmaf(xv.z, gv.z, acc);
    acc = fmaf(xv.w, gv.w, acc);
  }
  float lv[R];
#pragma unroll
  for (int rr = 0; rr < R; ++rr) lv[rr] = __shfl(acc, (l & ~7) + rr);
  int i0 = 0; float v0 = lv[0];
#pragma unroll
  for (int rr = 1; rr < R; ++rr) if (lv[rr] > v0) { v0 = lv[rr]; i0 = rr; }
  int i1 = (i0 == 0) ? 1 : 0; float v1 = lv[i1];
#pragma unroll
  for (int rr = 0; rr < R; ++rr)
    if (rr != i0 && lv[rr] > v1) { v1 = lv[rr]; i1 = rr; }
  float se = 0.f;
#pragma unroll
  for (int rr = 0; rr < R; ++rr) se += expf(lv[rr] - v0);
  float p = expf(acc - v0) / se;
  if (r == 0) {
    float e10 = expf(v1 - v0);
    top2[b] = make_int2(i0, i1);
    gwv[b]  = make_float2(1.f / (1.f + e10), e10 / (1.f + e10));
  }
  float pa = p;
  int   ca = (r == i0 ? 1 : 0) + (r == i1 ? 1 : 0);
#pragma unroll
  for (int m = 8; m < 64; m <<= 1) {
    pa += __shfl_xor(pa, m);
    ca += __shfl_xor(ca, m);
  }
  if (l < 8) { atomicAdd(&psl[r], pa); atomicAdd(&cl[r], ca); }
  __syncthreads();
  if (tid < R) {
    gcnt[blockIdx.x * R + tid] = cl[tid];
    gps [blockIdx.x * R + tid] = psl[tid];
  }
}

// ---------------- scatter: prefix over gate partials; no global atomics ----
// grid 256 x 64 thr; block g places samples [32g, 32g+32).
__global__ __launch_bounds__(64) void k_scatter(
    const int2* __restrict__ top2, const int* __restrict__ gcnt,
    const float* __restrict__ gps, int* __restrict__ counts, int* __restrict__ offs_g,
    int* __restrict__ list, int2* __restrict__ posmap, float* __restrict__ out_aux)
{
  __shared__ int cnt[R], pre[R], offs[R], lc[R];
  int tid = threadIdx.x;
  int g = blockIdx.x;
  if (tid < R) {
    int c = 0, pr = 0;
    for (int gg = 0; gg < 256; ++gg) {
      int v = gcnt[gg * R + tid];
      c += v;
      if (gg < g) pr += v;
    }
    cnt[tid] = min(c, B);
    pre[tid] = pr;
    lc[tid] = 0;
  }
  __syncthreads();
  if (tid == 0) {
    int o = 0;
    for (int r2 = 0; r2 < R; ++r2) { offs[r2] = o; o += (cnt[r2] + 127) & ~127; }
  }
  __syncthreads();
  if (tid < 32) {
    int b = g * 32 + tid;
    int2 t = top2[b];
    t.x &= 7; t.y &= 7;
    int p0 = atomicAdd(&lc[t.x], 1);
    int p1 = atomicAdd(&lc[t.y], 1);
    int i0 = min(offs[t.x] + pre[t.x] + p0, NPOS - 1);
    int i1 = min(offs[t.y] + pre[t.y] + p1, NPOS - 1);
    list[i0] = b * 2 + 0;
    list[i1] = b * 2 + 1;
    posmap[b] = make_int2(i0, i1);
  }
  if (g == 0 && tid == 0) {
    float s = 0.f;
    for (int r2 = 0; r2 < R; ++r2) {
      float pssum = 0.f;
      for (int gg = 0; gg < 256; ++gg) pssum += gps[gg * R + r2];
      s += (pssum / (float)B) * ((float)cnt[r2] / (float)B);
      counts[r2] = cnt[r2];
      offs_g[r2] = offs[r2];
    }
    out_aux[0] = (float)R * s * 0.05f;
  }
}

// ---------------- projgemm: unified (evn+xun) GEMM, K-split 2 --------------
// 128 thr; tile 128 rows x 64 h; 8x8/thread; 32-k stages; LDS 24 KB.
// grid 400 = 200 tiles x 2 ks. Tiles 0..63 evn; 64..199 xun (padded segs).
__global__ __launch_bounds__(128) void k_projgemm(
    const float* __restrict__ re, const float* __restrict__ x,
    const float* __restrict__ Vw, const float* __restrict__ Uw,
    const int* __restrict__ list, const int* __restrict__ counts,
    float* __restrict__ bufA, float* __restrict__ bufB)
{
  __shared__ __align__(16) float At[32 * 128];   // [k][row]
  __shared__ __align__(16) float Wt[32 * 64];    // [k][h]
  int tid = threadIdx.x;
  int bid = blockIdx.x;
  int tile = bid >> 1, ks = bid & 1;

  const float* Wsrc;
  const float* arow;
  int rowg0;
  if (tile < 64) {
    rowg0 = tile * 128;
    Wsrc = Vw + (size_t)(rowg0 >> 10) * (D * H);
    arow = re + (size_t)((rowg0 & 1023) + tid) * D;
  } else {
    int pos0 = (tile - 64) * 128;
    int tot = 0, r = 0;
    for (int rr = 0; rr < R; ++rr) {
      int seg = (min(counts[rr], B) + 127) & ~127;
      if (pos0 >= tot) r = rr;
      tot += seg;
    }
    if (pos0 >= tot) return;
    rowg0 = 8192 + pos0;
    Wsrc = Uw + (size_t)r * (D * H);
    int gl = list[min(pos0 + tid, NPOS - 1)];
    gl = min(max(gl, 0), 2 * B - 1);
    arow = x + (size_t)(gl >> 1) * D;
  }

  int rg = tid >> 3, hg = tid & 7;      // 16 row-groups x 8 h-groups
  float acc[8][8];
#pragma unroll
  for (int i = 0; i < 8; ++i)
#pragma unroll
    for (int j = 0; j < 8; ++j) acc[i][j] = 0.f;

  for (int kt = 0; kt < 6; ++kt) {
    int kb = ks * 192 + kt * 32;
    __syncthreads();
#pragma unroll
    for (int q = 0; q < 8; ++q) {                 // A: row-slice -> At[k][row]
      float4 v = *(const float4*)&arow[kb + q * 4];
      At[(q * 4 + 0) * 128 + tid] = v.x;
      At[(q * 4 + 1) * 128 + tid] = v.y;
      At[(q * 4 + 2) * 128 + tid] = v.z;
      At[(q * 4 + 3) * 128 + tid] = v.w;
    }
#pragma unroll
    for (int q = 0; q < 4; ++q) {                 // W: direct [k][h]
      int idx = tid + 128 * q;
      int k = idx >> 4, h4 = idx & 15;
      *(float4*)&Wt[k * 64 + h4 * 4] = *(const float4*)&Wsrc[(size_t)(kb + k) * H + h4 * 4];
    }
    __syncthreads();
#pragma unroll 8
    for (int k = 0; k < 32; ++k) {
      float4 xa = *(const float4*)&At[k * 128 + rg * 4];
      float4 xb = *(const float4*)&At[k * 128 + 64 + rg * 4];
      float4 wa = *(const float4*)&Wt[k * 64 + hg * 4];
      float4 wb = *(const float4*)&Wt[k * 64 + 32 + hg * 4];
      const float* pa = (const float*)&xa;
      const float* pb = (const float*)&xb;
      const float* qa = (const float*)&wa;
      const float* qb = (const float*)&wb;
#pragma unroll
      for (int i = 0; i < 4; ++i)
#pragma unroll
        for (int j = 0; j < 4; ++j) {
          acc[i][j]         = fmaf(pa[i], qa[j], acc[i][j]);
          acc[i][j + 4]     = fmaf(pa[i], qb[j], acc[i][j + 4]);
          acc[i + 4][j]     = fmaf(pb[i], qa[j], acc[i + 4][j]);
          acc[i + 4][j + 4] = fmaf(pb[i], qb[j], acc[i + 4][j + 4]);
        }
    }
  }
  float* dst = (ks ? bufB : bufA) + (size_t)rowg0 * H;
#pragma unroll
  for (int i = 0; i < 8; ++i) {
    int rl = (i < 4) ? (rg * 4 + i) : (64 + rg * 4 + i - 4);
    float4 o0, o1;
    o0.x = acc[i][0]; o0.y = acc[i][1]; o0.z = acc[i][2]; o0.w = acc[i][3];
    o1.x = acc[i][4]; o1.y = acc[i][5]; o1.z = acc[i][6]; o1.w = acc[i][7];
    *(float4*)&dst[rl * H + hg * 4]      = o0;
    *(float4*)&dst[rl * H + 32 + hg * 4] = o1;
  }
}

// ---------------- projfin: all rows: sum halves + bias + l2norm ------------
__global__ __launch_bounds__(256) void k_projfin(
    const float* __restrict__ bufA, const float* __restrict__ bufB,
    const float* __restrict__ Vb, const float* __restrict__ Ub,
    const int* __restrict__ offs, float* __restrict__ evnT,
    float* __restrict__ xunP)
{
  int tid = threadIdx.x;
  int lane = tid & 63;
  int row0 = blockIdx.x * 32 + (tid >> 6) * 8;
  bool isE = row0 < 8192;
  int r = 0;
  if (isE) {
    r = row0 >> 10;
  } else {
    int pos = row0 - 8192;
    for (int rr = 0; rr < R; ++rr) if (pos >= offs[rr]) r = rr;
  }
  float bias = isE ? Vb[r * H + lane] : Ub[r * H + lane];
#pragma unroll
  for (int i = 0; i < 8; ++i) {
    int row = row0 + i;
    float s = bufA[(size_t)row * H + lane] + bufB[(size_t)row * H + lane] + bias;
    float ss = s * s;
#pragma unroll
    for (int m = 1; m < 64; m <<= 1) ss += __shfl_xor(ss, m);
    float v = s / fmaxf(sqrtf(ss), 1e-12f);
    if (isE) evnT[(size_t)(r * 64 + lane) * 1024 + (row & 1023)] = v;
    else     xunP[(size_t)(row - 8192) * H + lane] = v;
  }
}

// ---------------- pass1: scores GEMM -> exp -> chunk sums ------------------
// tile 128 pos x 128 e; 8x8/thread; 32-k double-stage => LDS 32 KB, 5 blk/CU.
__global__ __launch_bounds__(256) void k_pass1(
    const float* __restrict__ evnT, const float* __restrict__ xunP,
    const int* __restrict__ counts, const int* __restrict__ offs,
    float* __restrict__ C)
{
  __shared__ __align__(16) float Xt[32 * 128];
  __shared__ __align__(16) float Et[32 * 128];
  int tid = threadIdx.x;
  int bid = blockIdx.x;
  int et    = bid & 7;
  int stile = (bid >> 3) & 63;
  int r     = bid >> 9;
  int cnt = min(counts[r], B);
  if (cnt <= 0 || stile * 128 >= cnt) return;
  int off = offs[r] + stile * 128;
  int n = min(128, cnt - stile * 128);
  int ebase = et * 128;

  int sg = tid >> 4, egr = tid & 15;
  float acc[8][8];
#pragma unroll
  for (int i = 0; i < 8; ++i)
#pragma unroll
    for (int j = 0; j < 8; ++j) acc[i][j] = 0.f;

  int srow = tid >> 1, shalf = tid & 1;
  int src = min(srow, n - 1);
  const float4* xsrc = (const float4*)(xunP + (size_t)(off + src) * H);

  for (int kst = 0; kst < 2; ++kst) {
    __syncthreads();
    {  // Xt: [pos][h] -> [h-local][s]
#pragma unroll
      for (int q = 0; q < 4; ++q) {
        float4 v = xsrc[kst * 8 + shalf * 4 + q];
        int hb = shalf * 16 + q * 4;
        Xt[(hb + 0) * 128 + srow] = v.x;
        Xt[(hb + 1) * 128 + srow] = v.y;
        Xt[(hb + 2) * 128 + srow] = v.z;
        Xt[(hb + 3) * 128 + srow] = v.w;
      }
    }
    {  // Et: evnT [h][ebase..+128)
#pragma unroll
      for (int q = 0; q < 4; ++q) {
        int idx = tid + 256 * q;
        int h = idx >> 5, e4 = idx & 31;
        *(float4*)&Et[h * 128 + e4 * 4] =
            *(const float4*)(evnT + (size_t)(r * 64 + kst * 32 + h) * 1024 + ebase + e4 * 4);
      }
    }
    __syncthreads();
#pragma unroll 4
    for (int k = 0; k < 32; ++k) {
      float4 xa = *(const float4*)&Xt[k * 128 + sg * 4];
      float4 xb = *(const float4*)&Xt[k * 128 + 64 + sg * 4];
      float4 ea = *(const float4*)&Et[k * 128 + egr * 4];
      float4 eb = *(const float4*)&Et[k * 128 + 64 + egr * 4];
      const float* pa = (const float*)&xa;
      const float* pb = (const float*)&xb;
      const float* qa = (const float*)&ea;
      const float* qb = (const float*)&eb;
#pragma unroll
      for (int i = 0; i < 4; ++i)
#pragma unroll
        for (int j = 0; j < 4; ++j) {
          acc[i][j]         = fmaf(pa[i], qa[j], acc[i][j]);
          acc[i][j + 4]     = fmaf(pa[i], qb[j], acc[i][j + 4]);
          acc[i + 4][j]     = fmaf(pb[i], qa[j], acc[i + 4][j]);
          acc[i + 4][j + 4] = fmaf(pb[i], qb[j], acc[i + 4][j + 4]);
        }
    }
  }

#pragma unroll
  for (int i = 0; i < 8; ++i) {
    float cA = expf(acc[i][0]) + expf(acc[i][1]) + expf(acc[i][2]) + expf(acc[i][3]);
    float cB = expf(acc[i][4]) + expf(acc[i][5]) + expf(acc[i][6]) + expf(acc[i][7]);
#pragma unroll
    for (int m = 1; m < 16; m <<= 1) {
      cA += __shfl_xor(cA, m);
      cB += __shfl_xor(cB, m);
    }
    int s = (i < 4) ? (sg * 4 + i) : (64 + sg * 4 + i - 4);
    if (egr == 0 && s < n) {
      C[(size_t)(off + s) * NCHUNK + et * 2]     = cA;
      C[(size_t)(off + s) * NCHUNK + et * 2 + 1] = cB;
    }
  }
}

// ---------------- pass2: chunk-level inverse-CDF, recompute 1 chunk --------
__global__ __launch_bounds__(256) void k_pass2(
    const float* __restrict__ evnT, const float* __restrict__ xunP,
    const float* __restrict__ C, const int2* __restrict__ top2,
    const int2* __restrict__ posmap, const float2* __restrict__ gwv,
    const float* __restrict__ rnd, float* __restrict__ out)
{
  int tid = threadIdx.x;
  int lane = tid & 63;
  int b = blockIdx.x * 4 + (tid >> 6);
  if (b >= B) return;
  int2 t2 = top2[b];
  t2.x &= 7; t2.y &= 7;
  int2 pm = posmap[b];
  pm.x = min(max(pm.x, 0), NPOS - 1);
  pm.y = min(max(pm.y, 0), NPOS - 1);
  float2 gw = gwv[b];
  float rv = rnd[b];

  const float4* C04 = (const float4*)(C + (size_t)pm.x * NCHUNK);
  const float4* C14 = (const float4*)(C + (size_t)pm.y * NCHUNK);
  float c0[NCHUNK], c1[NCHUNK];
#pragma unroll
  for (int q = 0; q < 4; ++q) {
    float4 v0 = C04[q], v1 = C14[q];
    c0[q*4+0]=v0.x; c0[q*4+1]=v0.y; c0[q*4+2]=v0.z; c0[q*4+3]=v0.w;
    c1[q*4+0]=v1.x; c1[q*4+1]=v1.y; c1[q*4+2]=v1.z; c1[q*4+3]=v1.w;
  }
  float S0 = 0.f, S1 = 0.f;
#pragma unroll
  for (int j = 0; j < NCHUNK; ++j) { S0 += c0[j]; S1 += c1[j]; }
  float a0 = gw.x / S0, a1 = gw.y / S1;
  int cstar = -1; float prefix = 0.f; float run = 0.f;
#pragma unroll
  for (int j = 0; j < NCHUNK; ++j) {
    float nrun = run + (c0[j] * a0 + c1[j] * a1);
    if (cstar < 0 && nrun > rv) { cstar = j; prefix = run; }
    run = nrun;
  }
  float rtgt = rv;
  if (cstar < 0) { cstar = 0; prefix = 0.f; rtgt = -1.0f; }

  float xu0 = xunP[(size_t)pm.x * H + lane];
  float xu1 = xunP[(size_t)pm.y * H + lane];
  const float* E0 = evnT + (size_t)t2.x * 64 * 1024 + cstar * CHUNK_E + lane;
  const float* E1 = evnT + (size_t)t2.y * 64 * 1024 + cstar * CHUNK_E + lane;
  float d0 = 0.f, d1 = 0.f;
#pragma unroll 16
  for (int h = 0; h < 64; ++h) {
    float w0 = __shfl(xu0, h);
    float w1 = __shfl(xu1, h);
    d0 = fmaf(E0[(size_t)h * 1024], w0, d0);
    d1 = fmaf(E1[(size_t)h * 1024], w1, d1);
  }
  float rea = expf(d0) * a0 + expf(d1) * a1;
  float sc = rea;
#pragma unroll
  for (int d = 1; d < 64; d <<= 1) {
    float o = __shfl_up(sc, d);
    if (lane >= d) sc += o;
  }
  float cum = prefix + sc;
  unsigned long long m2 = __ballot(cum > rtgt);
  int estar = (m2 == 0ull) ? 63 : (int)__builtin_ctzll(m2);
  float p = __shfl(rea, estar);
  if (lane == 0) {
    int sel = cstar * CHUNK_E + estar;
    out[b]     = (float)sel;
    out[B + b] = logf(p);
  }
}

// ---------------------------------------------------------------------------
extern "C" void kernel_launch(void* const* d_in, const int* in_sizes, int n_in,
                              void* d_out, int out_size, void* d_ws, size_t ws_size,
                              hipStream_t stream)
{
  (void)in_sizes; (void)n_in; (void)out_size; (void)ws_size;
  const float* x      = (const float*)d_in[0];
  const float* re     = (const float*)d_in[1];
  const float* rnd    = (const float*)d_in[2];
  const float* gate_w = (const float*)d_in[3];
  const float* gate_b = (const float*)d_in[4];
  const float* Uw     = (const float*)d_in[5];
  const float* Ub     = (const float*)d_in[6];
  const float* Vw     = (const float*)d_in[7];
  const float* Vb     = (const float*)d_in[8];
  char* ws = (char*)d_ws;
  int*    gcnt    = (int*)(ws + WS_GCNT);
  float*  gps     = (float*)(ws + WS_GPS);
  int*    counts  = (int*)(ws + WS_CNT);
  int*    offs    = (int*)(ws + WS_OFFS);
  int2*   top2    = (int2*)(ws + WS_TOP2);
  float2* gwv     = (float2*)(ws + WS_GW);
  int2*   posmap  = (int2*)(ws + WS_POSM);
  int*    list    = (int*)(ws + WS_LIST);
  float*  evnT    = (float*)(ws + WS_EVN);
  float*  xunP    = (float*)(ws + WS_XUN);
  float*  Cc      = (float*)(ws + WS_C);
  float*  bufA    = (float*)(ws + WS_BUFA);
  float*  bufB    = (float*)(ws + WS_BUFB);
  float* out = (float*)d_out;

  k_gate    <<<256,  256, 0, stream>>>(x, gate_w, gate_b, top2, gwv, gcnt, gps);
  k_scatter <<<256,  64,  0, stream>>>(top2, gcnt, gps, counts, offs, list, posmap, out + 2 * B);
  k_projgemm<<<400,  128, 0, stream>>>(re, x, Vw, Uw, list, counts, bufA, bufB);
  k_projfin <<<800,  256, 0, stream>>>(bufA, bufB, Vb, Ub, offs, evnT, xunP);
  k_pass1   <<<4096, 256, 0, stream>>>(evnT, xunP, counts, offs, Cc);
  k_pass2   <<<2048, 256, 0, stream>>>(evnT, xunP, Cc, top2, posmap, gwv, rnd, out);
}

// Round 11
// 192.876 us; speedup vs baseline: 1.1599x; 1.1599x over previous
//
#include <hip/hip_runtime.h>
#include <math.h>

// Problem constants
#define B 8192
#define E 1024
#define D 384
#define H 64
#define R 8
#define NCHUNK 16
#define CHUNK_E 64
#define NPOS 17408          // 16384 + 8*128 per-router pad-to-128
#define NROW 25600          // 8192 evn rows + NPOS xun rows

// ws byte offsets (total ~21.0 MB)
#define WS_CNT    0u          // int[8]  counts (atomic)
#define WS_CUR    32u         // int[8]  cursors (atomic)
#define WS_PS     64u         // float[8] prob sums (atomic)
#define WS_OFFS   96u         // int[8]  padded segment bases
#define WS_TOP2   256u        // int2[B]
#define WS_GW     65792u      // float2[B]
#define WS_POSM   131328u     // int2[B]
#define WS_LIST   196864u     // int[NPOS]
#define WS_EVN    266496u     // float[8*64*1024] evnT[r][h][e]
#define WS_XUN    2363648u    // float[NPOS*64]   xunP[pos][h]
#define WS_C      6820096u    // float[NPOS*16]   C[pos][chunk]
#define WS_BUFA   7934208u    // float[NROW*64]   K-half partial 0
#define WS_BUFB   14487808u   // float[NROW*64]   K-half partial 1

// ---------------- gate: lane = (sample, router); LDS-transposed gate_w -----
__global__ __launch_bounds__(256) void k_gate(
    const float* __restrict__ x, const float* __restrict__ gate_w,
    const float* __restrict__ gate_b, int2* __restrict__ top2,
    float2* __restrict__ gwv, int* __restrict__ counts, float* __restrict__ ps)
{
  __shared__ __align__(16) float gwT[R * 388];
  __shared__ float psl[R];
  __shared__ int   cl[R];
  int tid = threadIdx.x;
  for (int idx = tid; idx < D * R; idx += 256) {
    int k = idx >> 3, r = idx & 7;
    gwT[r * 388 + k] = gate_w[idx];
  }
  if (tid < R) { psl[tid] = 0.f; cl[tid] = 0; }
  __syncthreads();

  int l = tid & 63;
  int r = tid & 7;
  int b = blockIdx.x * 32 + (tid >> 3);
  float acc = gate_b[r];
  const float4* x4 = (const float4*)(x + (size_t)b * D);
  const float*  gr = gwT + r * 388;
#pragma unroll 4
  for (int q = 0; q < 96; ++q) {
    float4 xv = x4[q];
    float4 gv = *(const float4*)&gr[q * 4];
    acc = fmaf(xv.x, gv.x, acc);
    acc = fmaf(xv.y, gv.y, acc);
    acc = fmaf(xv.z, gv.z, acc);
    acc = fmaf(xv.w, gv.w, acc);
  }
  float lv[R];
#pragma unroll
  for (int rr = 0; rr < R; ++rr) lv[rr] = __shfl(acc, (l & ~7) + rr);
  int i0 = 0; float v0 = lv[0];
#pragma unroll
  for (int rr = 1; rr < R; ++rr) if (lv[rr] > v0) { v0 = lv[rr]; i0 = rr; }
  int i1 = (i0 == 0) ? 1 : 0; float v1 = lv[i1];
#pragma unroll
  for (int rr = 0; rr < R; ++rr)
    if (rr != i0 && lv[rr] > v1) { v1 = lv[rr]; i1 = rr; }
  float se = 0.f;
#pragma unroll
  for (int rr = 0; rr < R; ++rr) se += expf(lv[rr] - v0);
  float p = expf(acc - v0) / se;
  if (r == 0) {
    float e10 = expf(v1 - v0);
    top2[b] = make_int2(i0, i1);
    gwv[b]  = make_float2(1.f / (1.f + e10), e10 / (1.f + e10));
  }
  float pa = p;
  int   ca = (r == i0 ? 1 : 0) + (r == i1 ? 1 : 0);
#pragma unroll
  for (int m = 8; m < 64; m <<= 1) {
    pa += __shfl_xor(pa, m);
    ca += __shfl_xor(ca, m);
  }
  if (l < 8) { atomicAdd(&psl[r], pa); atomicAdd(&cl[r], ca); }
  __syncthreads();
  if (tid < R) { atomicAdd(&ps[tid], psl[tid]); atomicAdd(&counts[tid], cl[tid]); }
}

// ---------------- scatter: per-router lists (pad-128 bases) + aux + offs ---
__global__ __launch_bounds__(256) void k_scatter(
    const int2* __restrict__ top2, const int* __restrict__ counts,
    const float* __restrict__ ps, int* __restrict__ cursors,
    int* __restrict__ list, int2* __restrict__ posmap,
    int* __restrict__ offs_g, float* __restrict__ out_aux)
{
  __shared__ int lc[R];
  __shared__ int lbase[R];
  __shared__ int offs[R];
  int tid = threadIdx.x;
  if (tid < R) lc[tid] = 0;
  __syncthreads();
  if (tid == 0) {
    int o = 0;
    for (int r2 = 0; r2 < R; ++r2) { offs[r2] = o; o += (min(counts[r2], B) + 127) & ~127; }
  }
  __syncthreads();
  int b = min(blockIdx.x * 256 + tid, B - 1);
  int2 t = top2[b];
  t.x &= 7; t.y &= 7;
  int p0 = atomicAdd(&lc[t.x], 1);
  int p1 = atomicAdd(&lc[t.y], 1);
  __syncthreads();
  if (tid < R) lbase[tid] = atomicAdd(&cursors[tid], lc[tid]);
  __syncthreads();
  int i0 = min(offs[t.x] + lbase[t.x] + p0, NPOS - 1);
  int i1 = min(offs[t.y] + lbase[t.y] + p1, NPOS - 1);
  list[i0] = b * 2 + 0;
  list[i1] = b * 2 + 1;
  posmap[b] = make_int2(i0, i1);
  if (blockIdx.x == 0 && tid == 0) {
    float s = 0.f;
    for (int r2 = 0; r2 < R; ++r2) {
      s += (ps[r2] / (float)B) * ((float)min(counts[r2], B) / (float)B);
      offs_g[r2] = offs[r2];
    }
    out_aux[0] = (float)R * s * 0.05f;
  }
}

// ---------------- projgemm: unified (evn+xun) GEMM, K-split 2 --------------
// 128 threads; tile 128 rows x 64 h; 8x8/thread; 64-k stages; LDS 48 KB.
// grid 400 = 200 tiles x 2 ks. Tiles 0..63 evn; 64..199 xun (padded segs).
__global__ __launch_bounds__(128) void k_projgemm(
    const float* __restrict__ re, const float* __restrict__ x,
    const float* __restrict__ Vw, const float* __restrict__ Uw,
    const int* __restrict__ list, const int* __restrict__ counts,
    const int* __restrict__ offs, float* __restrict__ bufA,
    float* __restrict__ bufB)
{
  __shared__ __align__(16) float At[64 * 128];
  __shared__ __align__(16) float Wt[64 * 64];
  int tid = threadIdx.x;
  int bid = blockIdx.x;
  int tile = bid >> 1, ks = bid & 1;

  int srow = tid;
  const float* Wsrc;
  const float* arow;
  int rowg0;
  if (tile < 64) {
    rowg0 = tile * 128;
    Wsrc = Vw + (size_t)(rowg0 >> 10) * (D * H);
    arow = re + (size_t)((rowg0 & 1023) + srow) * D;
  } else {
    int pos0 = (tile - 64) * 128;
    int tot = offs[R - 1] + ((min(counts[R - 1], B) + 127) & ~127);
    if (pos0 >= tot) return;
    int r = 0;
    for (int rr = 0; rr < R; ++rr) if (pos0 >= offs[rr]) r = rr;
    rowg0 = 8192 + pos0;
    Wsrc = Uw + (size_t)r * (D * H);
    int gl = list[min(pos0 + srow, NPOS - 1)];
    gl = min(max(gl, 0), 2 * B - 1);
    arow = x + (size_t)(gl >> 1) * D;
  }

  int sg = tid >> 3, hg = tid & 7;      // 16 row-groups x 8 h-groups
  float acc[8][8];
#pragma unroll
  for (int i = 0; i < 8; ++i)
#pragma unroll
    for (int j = 0; j < 8; ++j) acc[i][j] = 0.f;

  for (int kt = 0; kt < 3; ++kt) {
    int kb = ks * 192 + kt * 64;
    __syncthreads();
#pragma unroll
    for (int q = 0; q < 16; ++q) {                // A: row-slice -> At[k][row]
      float4 v = *(const float4*)&arow[kb + q * 4];
      At[(q * 4 + 0) * 128 + srow] = v.x;
      At[(q * 4 + 1) * 128 + srow] = v.y;
      At[(q * 4 + 2) * 128 + srow] = v.z;
      At[(q * 4 + 3) * 128 + srow] = v.w;
    }
#pragma unroll
    for (int q = 0; q < 8; ++q) {                 // W: direct [k][h]
      int idx = tid + 128 * q;
      int k = idx >> 4, h4 = idx & 15;
      *(float4*)&Wt[k * 64 + h4 * 4] = *(const float4*)&Wsrc[(size_t)(kb + k) * H + h4 * 4];
    }
    __syncthreads();
#pragma unroll 8
    for (int k = 0; k < 64; ++k) {
      float4 xa = *(const float4*)&At[k * 128 + sg * 4];
      float4 xb = *(const float4*)&At[k * 128 + 64 + sg * 4];
      float4 wa = *(const float4*)&Wt[k * 64 + hg * 4];
      float4 wb = *(const float4*)&Wt[k * 64 + 32 + hg * 4];
      const float* pa = (const float*)&xa;
      const float* pb = (const float*)&xb;
      const float* qa = (const float*)&wa;
      const float* qb = (const float*)&wb;
#pragma unroll
      for (int i = 0; i < 4; ++i)
#pragma unroll
        for (int j = 0; j < 4; ++j) {
          acc[i][j]         = fmaf(pa[i], qa[j], acc[i][j]);
          acc[i][j + 4]     = fmaf(pa[i], qb[j], acc[i][j + 4]);
          acc[i + 4][j]     = fmaf(pb[i], qa[j], acc[i + 4][j]);
          acc[i + 4][j + 4] = fmaf(pb[i], qb[j], acc[i + 4][j + 4]);
        }
    }
  }
  float* dst = (ks ? bufB : bufA) + (size_t)rowg0 * H;
#pragma unroll
  for (int i = 0; i < 8; ++i) {
    int rl = (i < 4) ? (sg * 4 + i) : (64 + sg * 4 + i - 4);
    float4 o0, o1;
    o0.x = acc[i][0]; o0.y = acc[i][1]; o0.z = acc[i][2]; o0.w = acc[i][3];
    o1.x = acc[i][4]; o1.y = acc[i][5]; o1.z = acc[i][6]; o1.w = acc[i][7];
    *(float4*)&dst[rl * H + hg * 4]      = o0;
    *(float4*)&dst[rl * H + 32 + hg * 4] = o1;
  }
}

// ---------------- projfin: all rows: sum halves + bias + l2norm ------------
__global__ __launch_bounds__(256) void k_projfin(
    const float* __restrict__ bufA, const float* __restrict__ bufB,
    const float* __restrict__ Vb, const float* __restrict__ Ub,
    const int* __restrict__ offs, float* __restrict__ evnT,
    float* __restrict__ xunP)
{
  int tid = threadIdx.x;
  int lane = tid & 63;
  int row0 = blockIdx.x * 32 + (tid >> 6) * 8;
  bool isE = row0 < 8192;
  int r = 0;
  if (isE) {
    r = row0 >> 10;
  } else {
    int pos = row0 - 8192;
    for (int rr = 0; rr < R; ++rr) if (pos >= offs[rr]) r = rr;
  }
  float bias = isE ? Vb[r * H + lane] : Ub[r * H + lane];
#pragma unroll
  for (int i = 0; i < 8; ++i) {
    int row = row0 + i;
    float s = bufA[(size_t)row * H + lane] + bufB[(size_t)row * H + lane] + bias;
    float ss = s * s;
#pragma unroll
    for (int m = 1; m < 64; m <<= 1) ss += __shfl_xor(ss, m);
    float v = s / fmaxf(sqrtf(ss), 1e-12f);
    if (isE) evnT[(size_t)(r * 64 + lane) * 1024 + (row & 1023)] = v;
    else     xunP[(size_t)(row - 8192) * H + lane] = v;
  }
}

// ---------------- pass1: scores GEMM -> exp -> chunk sums ------------------
// tile 128 pos x 128 e; 8x8/thread; 32-k double-stage => LDS 32 KB.
__global__ __launch_bounds__(256) void k_pass1(
    const float* __restrict__ evnT, const float* __restrict__ xunP,
    const int* __restrict__ counts, const int* __restrict__ offs,
    float* __restrict__ C)
{
  __shared__ __align__(16) float Xt[32 * 128];
  __shared__ __align__(16) float Et[32 * 128];
  int tid = threadIdx.x;
  int bid = blockIdx.x;
  int et    = bid & 7;
  int stile = (bid >> 3) & 63;
  int r     = bid >> 9;
  int cnt = min(counts[r], B);
  if (cnt <= 0 || stile * 128 >= cnt) return;
  int off = offs[r] + stile * 128;
  int n = min(128, cnt - stile * 128);
  int ebase = et * 128;

  int sg = tid >> 4, egr = tid & 15;
  float acc[8][8];
#pragma unroll
  for (int i = 0; i < 8; ++i)
#pragma unroll
    for (int j = 0; j < 8; ++j) acc[i][j] = 0.f;

  int srow = tid >> 1, shalf = tid & 1;
  int src = min(srow, n - 1);
  const float4* xsrc = (const float4*)(xunP + (size_t)(off + src) * H);

  for (int kst = 0; kst < 2; ++kst) {
    __syncthreads();
    {  // Xt: [pos][h] -> [h-local][s]
#pragma unroll
      for (int q = 0; q < 4; ++q) {
        float4 v = xsrc[kst * 8 + shalf * 4 + q];
        int hb = shalf * 16 + q * 4;
        Xt[(hb + 0) * 128 + srow] = v.x;
        Xt[(hb + 1) * 128 + srow] = v.y;
        Xt[(hb + 2) * 128 + srow] = v.z;
        Xt[(hb + 3) * 128 + srow] = v.w;
      }
    }
    {  // Et: evnT [h][ebase..+128)
#pragma unroll
      for (int q = 0; q < 4; ++q) {
        int idx = tid + 256 * q;
        int h = idx >> 5, e4 = idx & 31;
        *(float4*)&Et[h * 128 + e4 * 4] =
            *(const float4*)(evnT + (size_t)(r * 64 + kst * 32 + h) * 1024 + ebase + e4 * 4);
      }
    }
    __syncthreads();
#pragma unroll 4
    for (int k = 0; k < 32; ++k) {
      float4 xa = *(const float4*)&Xt[k * 128 + sg * 4];
      float4 xb = *(const float4*)&Xt[k * 128 + 64 + sg * 4];
      float4 ea = *(const float4*)&Et[k * 128 + egr * 4];
      float4 eb = *(const float4*)&Et[k * 128 + 64 + egr * 4];
      const float* pa = (const float*)&xa;
      const float* pb = (const float*)&xb;
      const float* qa = (const float*)&ea;
      const float* qb = (const float*)&eb;
#pragma unroll
      for (int i = 0; i < 4; ++i)
#pragma unroll
        for (int j = 0; j < 4; ++j) {
          acc[i][j]         = fmaf(pa[i], qa[j], acc[i][j]);
          acc[i][j + 4]     = fmaf(pa[i], qb[j], acc[i][j + 4]);
          acc[i + 4][j]     = fmaf(pb[i], qa[j], acc[i + 4][j]);
          acc[i + 4][j + 4] = fmaf(pb[i], qb[j], acc[i + 4][j + 4]);
        }
    }
  }

#pragma unroll
  for (int i = 0; i < 8; ++i) {
    float cA = expf(acc[i][0]) + expf(acc[i][1]) + expf(acc[i][2]) + expf(acc[i][3]);
    float cB = expf(acc[i][4]) + expf(acc[i][5]) + expf(acc[i][6]) + expf(acc[i][7]);
#pragma unroll
    for (int m = 1; m < 16; m <<= 1) {
      cA += __shfl_xor(cA, m);
      cB += __shfl_xor(cB, m);
    }
    int s = (i < 4) ? (sg * 4 + i) : (64 + sg * 4 + i - 4);
    if (egr == 0 && s < n) {
      C[(size_t)(off + s) * NCHUNK + et * 2]     = cA;
      C[(size_t)(off + s) * NCHUNK + et * 2 + 1] = cB;
    }
  }
}

// ---------------- pass2: chunk-level inverse-CDF, recompute 1 chunk --------
__global__ __launch_bounds__(256) void k_pass2(
    const float* __restrict__ evnT, const float* __restrict__ xunP,
    const float* __restrict__ C, const int2* __restrict__ top2,
    const int2* __restrict__ posmap, const float2* __restrict__ gwv,
    const float* __restrict__ rnd, float* __restrict__ out)
{
  int tid = threadIdx.x;
  int lane = tid & 63;
  int b = blockIdx.x * 4 + (tid >> 6);
  if (b >= B) return;
  int2 t2 = top2[b];
  t2.x &= 7; t2.y &= 7;
  int2 pm = posmap[b];
  pm.x = min(max(pm.x, 0), NPOS - 1);
  pm.y = min(max(pm.y, 0), NPOS - 1);
  float2 gw = gwv[b];
  float rv = rnd[b];

  const float4* C04 = (const float4*)(C + (size_t)pm.x * NCHUNK);
  const float4* C14 = (const float4*)(C + (size_t)pm.y * NCHUNK);
  float c0[NCHUNK], c1[NCHUNK];
#pragma unroll
  for (int q = 0; q < 4; ++q) {
    float4 v0 = C04[q], v1 = C14[q];
    c0[q*4+0]=v0.x; c0[q*4+1]=v0.y; c0[q*4+2]=v0.z; c0[q*4+3]=v0.w;
    c1[q*4+0]=v1.x; c1[q*4+1]=v1.y; c1[q*4+2]=v1.z; c1[q*4+3]=v1.w;
  }
  float S0 = 0.f, S1 = 0.f;
#pragma unroll
  for (int j = 0; j < NCHUNK; ++j) { S0 += c0[j]; S1 += c1[j]; }
  float a0 = gw.x / S0, a1 = gw.y / S1;
  int cstar = -1; float prefix = 0.f; float run = 0.f;
#pragma unroll
  for (int j = 0; j < NCHUNK; ++j) {
    float nrun = run + (c0[j] * a0 + c1[j] * a1);
    if (cstar < 0 && nrun > rv) { cstar = j; prefix = run; }
    run = nrun;
  }
  float rtgt = rv;
  if (cstar < 0) { cstar = 0; prefix = 0.f; rtgt = -1.0f; }

  float xu0 = xunP[(size_t)pm.x * H + lane];
  float xu1 = xunP[(size_t)pm.y * H + lane];
  const float* E0 = evnT + (size_t)t2.x * 64 * 1024 + cstar * CHUNK_E + lane;
  const float* E1 = evnT + (size_t)t2.y * 64 * 1024 + cstar * CHUNK_E + lane;
  float d0 = 0.f, d1 = 0.f;
#pragma unroll 16
  for (int h = 0; h < 64; ++h) {
    float w0 = __shfl(xu0, h);
    float w1 = __shfl(xu1, h);
    d0 = fmaf(E0[(size_t)h * 1024], w0, d0);
    d1 = fmaf(E1[(size_t)h * 1024], w1, d1);
  }
  float rea = expf(d0) * a0 + expf(d1) * a1;
  float sc = rea;
#pragma unroll
  for (int d = 1; d < 64; d <<= 1) {
    float o = __shfl_up(sc, d);
    if (lane >= d) sc += o;
  }
  float cum = prefix + sc;
  unsigned long long m2 = __ballot(cum > rtgt);
  int estar = (m2 == 0ull) ? 63 : (int)__builtin_ctzll(m2);
  float p = __shfl(rea, estar);
  if (lane == 0) {
    int sel = cstar * CHUNK_E + estar;
    out[b]     = (float)sel;
    out[B + b] = logf(p);
  }
}

// ---------------------------------------------------------------------------
extern "C" void kernel_launch(void* const* d_in, const int* in_sizes, int n_in,
                              void* d_out, int out_size, void* d_ws, size_t ws_size,
                              hipStream_t stream)
{
  (void)in_sizes; (void)n_in; (void)out_size; (void)ws_size;
  const float* x      = (const float*)d_in[0];
  const float* re     = (const float*)d_in[1];
  const float* rnd    = (const float*)d_in[2];
  const float* gate_w = (const float*)d_in[3];
  const float* gate_b = (const float*)d_in[4];
  const float* Uw     = (const float*)d_in[5];
  const float* Ub     = (const float*)d_in[6];
  const float* Vw     = (const float*)d_in[7];
  const float* Vb     = (const float*)d_in[8];
  char* ws = (char*)d_ws;
  int*    counts  = (int*)(ws + WS_CNT);
  int*    cursors = (int*)(ws + WS_CUR);
  float*  ps      = (float*)(ws + WS_PS);
  int*    offs    = (int*)(ws + WS_OFFS);
  int2*   top2    = (int2*)(ws + WS_TOP2);
  float2* gwv     = (float2*)(ws + WS_GW);
  int2*   posmap  = (int2*)(ws + WS_POSM);
  int*    list    = (int*)(ws + WS_LIST);
  float*  evnT    = (float*)(ws + WS_EVN);
  float*  xunP    = (float*)(ws + WS_XUN);
  float*  Cc      = (float*)(ws + WS_C);
  float*  bufA    = (float*)(ws + WS_BUFA);
  float*  bufB    = (float*)(ws + WS_BUFB);
  float* out = (float*)d_out;

  hipMemsetAsync(ws, 0, 128, stream);
  k_gate    <<<256,  256, 0, stream>>>(x, gate_w, gate_b, top2, gwv, counts, ps);
  k_scatter <<<32,   256, 0, stream>>>(top2, counts, ps, cursors, list, posmap, offs, out + 2 * B);
  k_projgemm<<<400,  128, 0, stream>>>(re, x, Vw, Uw, list, counts, offs, bufA, bufB);
  k_projfin <<<800,  256, 0, stream>>>(bufA, bufB, Vb, Ub, offs, evnT, xunP);
  k_pass1   <<<4096, 256, 0, stream>>>(evnT, xunP, counts, offs, Cc);
  k_pass2   <<<2048, 256, 0, stream>>>(evnT, xunP, Cc, top2, posmap, gwv, rnd, out);
}

// Round 12
// 175.525 us; speedup vs baseline: 1.2746x; 1.0989x over previous
//
#include <hip/hip_runtime.h>
#include <math.h>

// Problem constants
#define B 8192
#define E 1024
#define D 384
#define H 64
#define R 8
#define NCHUNK 16
#define CHUNK_E 64
#define NPOS 17408          // 16384 + 8*128 per-router pad-to-128
#define NROW 25600          // 8192 evn rows + NPOS xun rows

// ws byte offsets (total ~21.0 MB; ws is 256 MiB per harness fill)
#define WS_CNT    0u          // int[8]  counts (atomic)
#define WS_CUR    32u         // int[8]  cursors (atomic)
#define WS_PS     64u         // float[8] prob sums (atomic)
#define WS_OFFS   96u         // int[8]  padded segment bases
#define WS_TOP2   256u        // int2[B]
#define WS_GW     65792u      // float2[B]
#define WS_POSM   131328u     // int2[B]
#define WS_LIST   196864u     // int[NPOS]
#define WS_EVN    266496u     // float[8*64*1024] evnT[r][h][e]
#define WS_XUN    2363648u    // float[NPOS*64]   xunP[pos][h]
#define WS_C      6820096u    // float[NPOS*16]   C[pos][chunk]
#define WS_BUFA   7934208u    // float[NROW*64]   K-half partial 0
#define WS_BUFB   14487808u   // float[NROW*64]   K-half partial 1

// ---------------- gate: lane = (sample, router); LDS-transposed gate_w -----
__global__ __launch_bounds__(256) void k_gate(
    const float* __restrict__ x, const float* __restrict__ gate_w,
    const float* __restrict__ gate_b, int2* __restrict__ top2,
    float2* __restrict__ gwv, int* __restrict__ counts, float* __restrict__ ps)
{
  __shared__ __align__(16) float gwT[R * 388];
  __shared__ float psl[R];
  __shared__ int   cl[R];
  int tid = threadIdx.x;
  for (int idx = tid; idx < D * R; idx += 256) {
    int k = idx >> 3, r = idx & 7;
    gwT[r * 388 + k] = gate_w[idx];
  }
  if (tid < R) { psl[tid] = 0.f; cl[tid] = 0; }
  __syncthreads();

  int l = tid & 63;
  int r = tid & 7;
  int b = blockIdx.x * 32 + (tid >> 3);
  float acc = gate_b[r];
  const float4* x4 = (const float4*)(x + (size_t)b * D);
  const float*  gr = gwT + r * 388;
#pragma unroll 4
  for (int q = 0; q < 96; ++q) {
    float4 xv = x4[q];
    float4 gv = *(const float4*)&gr[q * 4];
    acc = fmaf(xv.x, gv.x, acc);
    acc = fmaf(xv.y, gv.y, acc);
    acc = fmaf(xv.z, gv.z, acc);
    acc = fmaf(xv.w, gv.w, acc);
  }
  float lv[R];
#pragma unroll
  for (int rr = 0; rr < R; ++rr) lv[rr] = __shfl(acc, (l & ~7) + rr);
  int i0 = 0; float v0 = lv[0];
#pragma unroll
  for (int rr = 1; rr < R; ++rr) if (lv[rr] > v0) { v0 = lv[rr]; i0 = rr; }
  int i1 = (i0 == 0) ? 1 : 0; float v1 = lv[i1];
#pragma unroll
  for (int rr = 0; rr < R; ++rr)
    if (rr != i0 && lv[rr] > v1) { v1 = lv[rr]; i1 = rr; }
  float se = 0.f;
#pragma unroll
  for (int rr = 0; rr < R; ++rr) se += expf(lv[rr] - v0);
  float p = expf(acc - v0) / se;
  if (r == 0) {
    float e10 = expf(v1 - v0);
    top2[b] = make_int2(i0, i1);
    gwv[b]  = make_float2(1.f / (1.f + e10), e10 / (1.f + e10));
  }
  float pa = p;
  int   ca = (r == i0 ? 1 : 0) + (r == i1 ? 1 : 0);
#pragma unroll
  for (int m = 8; m < 64; m <<= 1) {
    pa += __shfl_xor(pa, m);
    ca += __shfl_xor(ca, m);
  }
  if (l < 8) { atomicAdd(&psl[r], pa); atomicAdd(&cl[r], ca); }
  __syncthreads();
  if (tid < R) { atomicAdd(&ps[tid], psl[tid]); atomicAdd(&counts[tid], cl[tid]); }
}

// ---------------- scatter: per-router lists (pad-128 bases) + aux + offs ---
__global__ __launch_bounds__(256) void k_scatter(
    const int2* __restrict__ top2, const int* __restrict__ counts,
    const float* __restrict__ ps, int* __restrict__ cursors,
    int* __restrict__ list, int2* __restrict__ posmap,
    int* __restrict__ offs_g, float* __restrict__ out_aux)
{
  __shared__ int lc[R];
  __shared__ int lbase[R];
  __shared__ int offs[R];
  int tid = threadIdx.x;
  if (tid < R) lc[tid] = 0;
  __syncthreads();
  if (tid == 0) {
    int o = 0;
    for (int r2 = 0; r2 < R; ++r2) { offs[r2] = o; o += (min(counts[r2], B) + 127) & ~127; }
  }
  __syncthreads();
  int b = min(blockIdx.x * 256 + tid, B - 1);
  int2 t = top2[b];
  t.x &= 7; t.y &= 7;
  int p0 = atomicAdd(&lc[t.x], 1);
  int p1 = atomicAdd(&lc[t.y], 1);
  __syncthreads();
  if (tid < R) lbase[tid] = atomicAdd(&cursors[tid], lc[tid]);
  __syncthreads();
  int i0 = min(offs[t.x] + lbase[t.x] + p0, NPOS - 1);
  int i1 = min(offs[t.y] + lbase[t.y] + p1, NPOS - 1);
  list[i0] = b * 2 + 0;
  list[i1] = b * 2 + 1;
  posmap[b] = make_int2(i0, i1);
  if (blockIdx.x == 0 && tid == 0) {
    float s = 0.f;
    for (int r2 = 0; r2 < R; ++r2) {
      s += (ps[r2] / (float)B) * ((float)min(counts[r2], B) / (float)B);
      offs_g[r2] = offs[r2];
    }
    out_aux[0] = (float)R * s * 0.05f;
  }
}

// ---------------- projgemm: unified (evn+xun) GEMM, K-split 2 --------------
// 256 threads; tile 64 rows x 64 h; 4x4/thread; 3 k-stages of 64; LDS 32 KB.
// grid 800 = 400 tiles x 2 ks. Tiles 0..127 evn; 128..399 xun (pad-128 segs).
// All LDS patterns <=2-way: A compute-read is 4-address broadcast, W-read
// 2-way, staging writes consecutive.
__global__ __launch_bounds__(256) void k_projgemm(
    const float* __restrict__ re, const float* __restrict__ x,
    const float* __restrict__ Vw, const float* __restrict__ Uw,
    const int* __restrict__ list, const int* __restrict__ counts,
    const int* __restrict__ offs, float* __restrict__ bufA,
    float* __restrict__ bufB)
{
  __shared__ __align__(16) float At[64 * 64];   // [k][row]
  __shared__ __align__(16) float Wt[64 * 64];   // [k][h]
  int tid = threadIdx.x;
  int bid = blockIdx.x;
  int tile = bid >> 1, ks = bid & 1;
  int rowg0 = tile * 64;

  int srow = tid & 63, kq = tid >> 6;           // staging roles
  const float* Wsrc;
  const float* arow;
  if (tile < 128) {
    Wsrc = Vw + (size_t)(rowg0 >> 10) * (D * H);
    arow = re + (size_t)((rowg0 & 1023) + srow) * D;
  } else {
    int pos0 = rowg0 - 8192;
    int tot = offs[R - 1] + ((min(counts[R - 1], B) + 127) & ~127);
    if (pos0 >= tot) return;
    int r = 0;
    for (int rr = 0; rr < R; ++rr) if (pos0 >= offs[rr]) r = rr;
    Wsrc = Uw + (size_t)r * (D * H);
    int gl = list[min(pos0 + srow, NPOS - 1)];
    gl = min(max(gl, 0), 2 * B - 1);
    arow = x + (size_t)(gl >> 1) * D;
  }

  int tr = tid >> 4, tc = tid & 15;             // compute roles: 16 x 16
  float acc[4][4];
#pragma unroll
  for (int i = 0; i < 4; ++i)
#pragma unroll
    for (int j = 0; j < 4; ++j) acc[i][j] = 0.f;

  for (int kt = 0; kt < 3; ++kt) {
    int kb = ks * 192 + kt * 64;
    __syncthreads();
#pragma unroll
    for (int q = 0; q < 4; ++q) {               // A: [row][k] -> At[k][row]
      float4 v = *(const float4*)&arow[kb + (kq + 4 * q) * 4];
      int k0 = (kq + 4 * q) * 4;
      At[(k0 + 0) * 64 + srow] = v.x;
      At[(k0 + 1) * 64 + srow] = v.y;
      At[(k0 + 2) * 64 + srow] = v.z;
      At[(k0 + 3) * 64 + srow] = v.w;
    }
#pragma unroll
    for (int q = 0; q < 4; ++q) {               // W: direct [k][h]
      int idx = tid + 256 * q;
      int k = idx >> 4, h4 = idx & 15;
      *(float4*)&Wt[k * 64 + h4 * 4] = *(const float4*)&Wsrc[(size_t)(kb + k) * H + h4 * 4];
    }
    __syncthreads();
#pragma unroll 8
    for (int k = 0; k < 64; ++k) {
      float4 a4 = *(const float4*)&At[k * 64 + tr * 4];
      float4 w4 = *(const float4*)&Wt[k * 64 + tc * 4];
      const float* ap = (const float*)&a4;
      const float* wp = (const float*)&w4;
#pragma unroll
      for (int i = 0; i < 4; ++i)
#pragma unroll
        for (int j = 0; j < 4; ++j) acc[i][j] = fmaf(ap[i], wp[j], acc[i][j]);
    }
  }
  float* dst = (ks ? bufB : bufA) + (size_t)rowg0 * H;
#pragma unroll
  for (int i = 0; i < 4; ++i) {
    float4 o;
    o.x = acc[i][0]; o.y = acc[i][1]; o.z = acc[i][2]; o.w = acc[i][3];
    *(float4*)&dst[(tr * 4 + i) * H + tc * 4] = o;
  }
}

// ---------------- projfin: all rows: sum halves + bias + l2norm ------------
__global__ __launch_bounds__(256) void k_projfin(
    const float* __restrict__ bufA, const float* __restrict__ bufB,
    const float* __restrict__ Vb, const float* __restrict__ Ub,
    const int* __restrict__ offs, float* __restrict__ evnT,
    float* __restrict__ xunP)
{
  int tid = threadIdx.x;
  int lane = tid & 63;
  int row0 = blockIdx.x * 32 + (tid >> 6) * 8;
  bool isE = row0 < 8192;
  int r = 0;
  if (isE) {
    r = row0 >> 10;
  } else {
    int pos = row0 - 8192;
    for (int rr = 0; rr < R; ++rr) if (pos >= offs[rr]) r = rr;
  }
  float bias = isE ? Vb[r * H + lane] : Ub[r * H + lane];
#pragma unroll
  for (int i = 0; i < 8; ++i) {
    int row = row0 + i;
    float s = bufA[(size_t)row * H + lane] + bufB[(size_t)row * H + lane] + bias;
    float ss = s * s;
#pragma unroll
    for (int m = 1; m < 64; m <<= 1) ss += __shfl_xor(ss, m);
    float v = s / fmaxf(sqrtf(ss), 1e-12f);
    if (isE) evnT[(size_t)(r * 64 + lane) * 1024 + (row & 1023)] = v;
    else     xunP[(size_t)(row - 8192) * H + lane] = v;
  }
}

// ---------------- pass1: scores GEMM -> __expf -> chunk sums ---------------
// tile 128 pos x 128 e; 8x8/thread; 32-k double-stage => LDS 32 KB.
__global__ __launch_bounds__(256) void k_pass1(
    const float* __restrict__ evnT, const float* __restrict__ xunP,
    const int* __restrict__ counts, const int* __restrict__ offs,
    float* __restrict__ C)
{
  __shared__ __align__(16) float Xt[32 * 128];
  __shared__ __align__(16) float Et[32 * 128];
  int tid = threadIdx.x;
  int bid = blockIdx.x;
  int et    = bid & 7;
  int stile = (bid >> 3) & 63;
  int r     = bid >> 9;
  int cnt = min(counts[r], B);
  if (cnt <= 0 || stile * 128 >= cnt) return;
  int off = offs[r] + stile * 128;
  int n = min(128, cnt - stile * 128);
  int ebase = et * 128;

  int sg = tid >> 4, egr = tid & 15;
  float acc[8][8];
#pragma unroll
  for (int i = 0; i < 8; ++i)
#pragma unroll
    for (int j = 0; j < 8; ++j) acc[i][j] = 0.f;

  int srow = tid >> 1, shalf = tid & 1;
  int src = min(srow, n - 1);
  const float4* xsrc = (const float4*)(xunP + (size_t)(off + src) * H);

  for (int kst = 0; kst < 2; ++kst) {
    __syncthreads();
    {  // Xt: [pos][h] -> [h-local][s]
#pragma unroll
      for (int q = 0; q < 4; ++q) {
        float4 v = xsrc[kst * 8 + shalf * 4 + q];
        int hb = shalf * 16 + q * 4;
        Xt[(hb + 0) * 128 + srow] = v.x;
        Xt[(hb + 1) * 128 + srow] = v.y;
        Xt[(hb + 2) * 128 + srow] = v.z;
        Xt[(hb + 3) * 128 + srow] = v.w;
      }
    }
    {  // Et: evnT [h][ebase..+128)
#pragma unroll
      for (int q = 0; q < 4; ++q) {
        int idx = tid + 256 * q;
        int h = idx >> 5, e4 = idx & 31;
        *(float4*)&Et[h * 128 + e4 * 4] =
            *(const float4*)(evnT + (size_t)(r * 64 + kst * 32 + h) * 1024 + ebase + e4 * 4);
      }
    }
    __syncthreads();
#pragma unroll 4
    for (int k = 0; k < 32; ++k) {
      float4 xa = *(const float4*)&Xt[k * 128 + sg * 4];
      float4 xb = *(const float4*)&Xt[k * 128 + 64 + sg * 4];
      float4 ea = *(const float4*)&Et[k * 128 + egr * 4];
      float4 eb = *(const float4*)&Et[k * 128 + 64 + egr * 4];
      const float* pa = (const float*)&xa;
      const float* pb = (const float*)&xb;
      const float* qa = (const float*)&ea;
      const float* qb = (const float*)&eb;
#pragma unroll
      for (int i = 0; i < 4; ++i)
#pragma unroll
        for (int j = 0; j < 4; ++j) {
          acc[i][j]         = fmaf(pa[i], qa[j], acc[i][j]);
          acc[i][j + 4]     = fmaf(pa[i], qb[j], acc[i][j + 4]);
          acc[i + 4][j]     = fmaf(pb[i], qa[j], acc[i + 4][j]);
          acc[i + 4][j + 4] = fmaf(pb[i], qb[j], acc[i + 4][j + 4]);
        }
    }
  }

#pragma unroll
  for (int i = 0; i < 8; ++i) {
    float cA = __expf(acc[i][0]) + __expf(acc[i][1]) + __expf(acc[i][2]) + __expf(acc[i][3]);
    float cB = __expf(acc[i][4]) + __expf(acc[i][5]) + __expf(acc[i][6]) + __expf(acc[i][7]);
#pragma unroll
    for (int m = 1; m < 16; m <<= 1) {
      cA += __shfl_xor(cA, m);
      cB += __shfl_xor(cB, m);
    }
    int s = (i < 4) ? (sg * 4 + i) : (64 + sg * 4 + i - 4);
    if (egr == 0 && s < n) {
      C[(size_t)(off + s) * NCHUNK + et * 2]     = cA;
      C[(size_t)(off + s) * NCHUNK + et * 2 + 1] = cB;
    }
  }
}

// ---------------- pass2: chunk-level inverse-CDF, recompute 1 chunk --------
__global__ __launch_bounds__(256) void k_pass2(
    const float* __restrict__ evnT, const float* __restrict__ xunP,
    const float* __restrict__ C, const int2* __restrict__ top2,
    const int2* __restrict__ posmap, const float2* __restrict__ gwv,
    const float* __restrict__ rnd, float* __restrict__ out)
{
  int tid = threadIdx.x;
  int lane = tid & 63;
  int b = blockIdx.x * 4 + (tid >> 6);
  if (b >= B) return;
  int2 t2 = top2[b];
  t2.x &= 7; t2.y &= 7;
  int2 pm = posmap[b];
  pm.x = min(max(pm.x, 0), NPOS - 1);
  pm.y = min(max(pm.y, 0), NPOS - 1);
  float2 gw = gwv[b];
  float rv = rnd[b];

  const float4* C04 = (const float4*)(C + (size_t)pm.x * NCHUNK);
  const float4* C14 = (const float4*)(C + (size_t)pm.y * NCHUNK);
  float c0[NCHUNK], c1[NCHUNK];
#pragma unroll
  for (int q = 0; q < 4; ++q) {
    float4 v0 = C04[q], v1 = C14[q];
    c0[q*4+0]=v0.x; c0[q*4+1]=v0.y; c0[q*4+2]=v0.z; c0[q*4+3]=v0.w;
    c1[q*4+0]=v1.x; c1[q*4+1]=v1.y; c1[q*4+2]=v1.z; c1[q*4+3]=v1.w;
  }
  float S0 = 0.f, S1 = 0.f;
#pragma unroll
  for (int j = 0; j < NCHUNK; ++j) { S0 += c0[j]; S1 += c1[j]; }
  float a0 = gw.x / S0, a1 = gw.y / S1;
  int cstar = -1; float prefix = 0.f; float run = 0.f;
#pragma unroll
  for (int j = 0; j < NCHUNK; ++j) {
    float nrun = run + (c0[j] * a0 + c1[j] * a1);
    if (cstar < 0 && nrun > rv) { cstar = j; prefix = run; }
    run = nrun;
  }
  float rtgt = rv;
  if (cstar < 0) { cstar = 0; prefix = 0.f; rtgt = -1.0f; }

  float xu0 = xunP[(size_t)pm.x * H + lane];
  float xu1 = xunP[(size_t)pm.y * H + lane];
  const float* E0 = evnT + (size_t)t2.x * 64 * 1024 + cstar * CHUNK_E + lane;
  const float* E1 = evnT + (size_t)t2.y * 64 * 1024 + cstar * CHUNK_E + lane;
  float d0 = 0.f, d1 = 0.f;
#pragma unroll 16
  for (int h = 0; h < 64; ++h) {
    float w0 = __shfl(xu0, h);
    float w1 = __shfl(xu1, h);
    d0 = fmaf(E0[(size_t)h * 1024], w0, d0);
    d1 = fmaf(E1[(size_t)h * 1024], w1, d1);
  }
  float rea = __expf(d0) * a0 + __expf(d1) * a1;
  float sc = rea;
#pragma unroll
  for (int d = 1; d < 64; d <<= 1) {
    float o = __shfl_up(sc, d);
    if (lane >= d) sc += o;
  }
  float cum = prefix + sc;
  unsigned long long m2 = __ballot(cum > rtgt);
  int estar = (m2 == 0ull) ? 63 : (int)__builtin_ctzll(m2);
  float p = __shfl(rea, estar);
  if (lane == 0) {
    int sel = cstar * CHUNK_E + estar;
    out[b]     = (float)sel;
    out[B + b] = logf(p);
  }
}

// ---------------------------------------------------------------------------
extern "C" void kernel_launch(void* const* d_in, const int* in_sizes, int n_in,
                              void* d_out, int out_size, void* d_ws, size_t ws_size,
                              hipStream_t stream)
{
  (void)in_sizes; (void)n_in; (void)out_size; (void)ws_size;
  const float* x      = (const float*)d_in[0];
  const float* re     = (const float*)d_in[1];
  const float* rnd    = (const float*)d_in[2];
  const float* gate_w = (const float*)d_in[3];
  const float* gate_b = (const float*)d_in[4];
  const float* Uw     = (const float*)d_in[5];
  const float* Ub     = (const float*)d_in[6];
  const float* Vw     = (const float*)d_in[7];
  const float* Vb     = (const float*)d_in[8];
  char* ws = (char*)d_ws;
  int*    counts  = (int*)(ws + WS_CNT);
  int*    cursors = (int*)(ws + WS_CUR);
  float*  ps      = (float*)(ws + WS_PS);
  int*    offs    = (int*)(ws + WS_OFFS);
  int2*   top2    = (int2*)(ws + WS_TOP2);
  float2* gwv     = (float2*)(ws + WS_GW);
  int2*   posmap  = (int2*)(ws + WS_POSM);
  int*    list    = (int*)(ws + WS_LIST);
  float*  evnT    = (float*)(ws + WS_EVN);
  float*  xunP    = (float*)(ws + WS_XUN);
  float*  Cc      = (float*)(ws + WS_C);
  float*  bufA    = (float*)(ws + WS_BUFA);
  float*  bufB    = (float*)(ws + WS_BUFB);
  float* out = (float*)d_out;

  hipMemsetAsync(ws, 0, 128, stream);
  k_gate    <<<256,  256, 0, stream>>>(x, gate_w, gate_b, top2, gwv, counts, ps);
  k_scatter <<<32,   256, 0, stream>>>(top2, counts, ps, cursors, list, posmap, offs, out + 2 * B);
  k_projgemm<<<800,  256, 0, stream>>>(re, x, Vw, Uw, list, counts, offs, bufA, bufB);
  k_projfin <<<800,  256, 0, stream>>>(bufA, bufB, Vb, Ub, offs, evnT, xunP);
  k_pass1   <<<4096, 256, 0, stream>>>(evnT, xunP, counts, offs, Cc);
  k_pass2   <<<2048, 256, 0, stream>>>(evnT, xunP, Cc, top2, posmap, gwv, rnd, out);
}